// Round 1
// baseline (745.683 us; speedup 1.0000x reference)
//
#include <hip/hip_runtime.h>
#include <hip/hip_bf16.h>
#include <stdint.h>

#define B_    256
#define T_    512
#define N_    256
#define START_ 254
#define STOP_  255
#define GCOLS 16
#define NDB   (B_ / GCOLS)   // 16 denominator blocks
#define LOG2E 1.4426950408889634f
#define LN2   0.6931471805599453f
#define VPITCH 264           // shorts per V row; 528 B => 2-way-max bank aliasing (free)

typedef __attribute__((ext_vector_type(8))) short short8;
typedef __attribute__((ext_vector_type(4))) short short4_t;
typedef __attribute__((ext_vector_type(4))) float floatx4;

__device__ __forceinline__ short f2bf(float f) {
    uint32_t u = __builtin_bit_cast(uint32_t, f);
    u = (u + 0x7FFFu + ((u >> 16) & 1u)) >> 16;   // RNE
    return (short)(uint16_t)u;
}

// Block layout (denominator): 512 threads = 8 waves. Wave w owns output rows
// j in [32w, 32w+32) (2 M-tiles of 16). Lane l: q=l>>4, b=l&15 (batch column).
// E (=exp2(trans*log2e), bf16) lives permanently in VGPRs as MFMA A-fragments.
// V (16 columns x 256 states, bf16) lives in LDS, layout [b][k], pitch VPITCH.
__global__ __launch_bounds__(512, 2) void crf_kernel(
    const float* __restrict__ inputs, const float* __restrict__ trans,
    const int* __restrict__ tags, const int* __restrict__ mask,
    float* __restrict__ out)
{
    __shared__ short Vlds[GCOLS * VPITCH];
    __shared__ float mbuf[GCOLS * 8];
    __shared__ float sbuf[GCOLS * 8];
    __shared__ float nred[8];
    __shared__ int   nredi[8];

    if (blockIdx.x >= NDB) {
        // ---------------- numerator path: one batch per block ----------------
        const int bb = blockIdx.x - NDB;
        const int t  = threadIdx.x;            // 0..511
        const int tg = tags[bb * T_ + t];
        const float fm = (float)mask[bb * T_ + t];
        float part = 0.f;
        if (t >= 1)      part += trans[tg * N_ + tags[bb * T_ + t - 1]] * fm;
        if (t <= T_ - 2) part += inputs[((size_t)bb * T_ + t) * N_ + tg] * fm;
        int ms = mask[bb * T_ + t];
        #pragma unroll
        for (int off = 1; off < 64; off <<= 1) {
            part += __shfl_xor(part, off, 64);
            ms   += __shfl_xor(ms, off, 64);
        }
        if ((t & 63) == 0) { nred[t >> 6] = part; nredi[t >> 6] = ms; }
        __syncthreads();
        if (t == 0) {
            float tot = 0.f; int mtot = 0;
            for (int i = 0; i < 8; ++i) { tot += nred[i]; mtot += nredi[i]; }
            tot += trans[tags[bb * T_] * N_ + START_];
            const int last = mtot - 1;
            const int lt = tags[bb * T_ + last];
            tot += trans[STOP_ * N_ + lt]
                 + inputs[((size_t)bb * T_ + (T_ - 1)) * N_ + lt]
                   * (float)mask[bb * T_ + T_ - 1];
            atomicAdd(out, tot);
        }
        return;
    }

    // ---------------- denominator path ----------------
    const int tid = threadIdx.x;
    const int w = tid >> 6;          // wave 0..7
    const int l = tid & 63;
    const int q = l >> 4;            // quad 0..3
    const int b = l & 15;            // batch column within block / A-row m-index
    const int bg = blockIdx.x * GCOLS + b;
    const int j0 = 32 * w + 4 * q;   // C/D row base (+16*mt)

    // ---- load E as persistent A-fragments: lane holds E[32w+16mt+(l&15)][32kt+8q+jj]
    short8 afrag[2][8];
    #pragma unroll
    for (int mt = 0; mt < 2; ++mt) {
        const int row = 32 * w + 16 * mt + b;
        #pragma unroll
        for (int kt = 0; kt < 8; ++kt) {
            const float* p = trans + row * N_ + kt * 32 + q * 8;
            floatx4 t0 = *(const floatx4*)p;
            floatx4 t1 = *(const floatx4*)(p + 4);
            short8 a;
            a[0] = f2bf(exp2f(t0[0] * LOG2E));
            a[1] = f2bf(exp2f(t0[1] * LOG2E));
            a[2] = f2bf(exp2f(t0[2] * LOG2E));
            a[3] = f2bf(exp2f(t0[3] * LOG2E));
            a[4] = f2bf(exp2f(t1[0] * LOG2E));
            a[5] = f2bf(exp2f(t1[1] * LOG2E));
            a[6] = f2bf(exp2f(t1[2] * LOG2E));
            a[7] = f2bf(exp2f(t1[3] * LOG2E));
            afrag[mt][kt] = a;
        }
    }

    const float* emitp = inputs + (size_t)bg * T_ * N_;
    float C = 0.f;        // per-column log2-scale offset (invariant: alpha2 = C + log2(V))
    float colsum = 0.f;   // sum_i V[i,b]  (for mask==0 step semantics)
    float u[2][4];        // current unnormalized new column values (this lane's 8 rows)

    // normalize u -> V (bf16, LDS), update C and colsum. 2 barriers.
    auto epilogue = [&]() {
        float mx = 0.f, sm = 0.f;   // u >= 0
        #pragma unroll
        for (int mt = 0; mt < 2; ++mt)
            #pragma unroll
            for (int r = 0; r < 4; ++r) { mx = fmaxf(mx, u[mt][r]); sm += u[mt][r]; }
        mx = fmaxf(mx, __shfl_xor(mx, 16, 64)); sm += __shfl_xor(sm, 16, 64);
        mx = fmaxf(mx, __shfl_xor(mx, 32, 64)); sm += __shfl_xor(sm, 32, 64);
        if (l < 16) { mbuf[b * 8 + w] = mx; sbuf[b * 8 + w] = sm; }
        __syncthreads();
        floatx4 m0 = *(const floatx4*)&mbuf[b * 8];
        floatx4 m1 = *(const floatx4*)&mbuf[b * 8 + 4];
        floatx4 s0 = *(const floatx4*)&sbuf[b * 8];
        floatx4 s1 = *(const floatx4*)&sbuf[b * 8 + 4];
        float cmax = fmaxf(fmaxf(fmaxf(m0[0], m0[1]), fmaxf(m0[2], m0[3])),
                           fmaxf(fmaxf(m1[0], m1[1]), fmaxf(m1[2], m1[3])));
        float csum = ((s0[0] + s0[1]) + (s0[2] + s0[3])) +
                     ((s1[0] + s1[1]) + (s1[2] + s1[3]));
        float rs = 1.0f / cmax;
        C -= log2f(rs);            // exact bookkeeping of applied scale
        colsum = csum * rs;
        #pragma unroll
        for (int mt = 0; mt < 2; ++mt) {
            short4_t vv;
            #pragma unroll
            for (int r = 0; r < 4; ++r) { u[mt][r] *= rs; vv[r] = f2bf(u[mt][r]); }
            *(short4_t*)&Vlds[b * VPITCH + j0 + 16 * mt] = vv;
        }
        __syncthreads();
    };

    // ---- init: alpha0 = trans[:,START] + inputs[:,0,:]  (log2 domain)
    #pragma unroll
    for (int mt = 0; mt < 2; ++mt) {
        floatx4 em = *(const floatx4*)(emitp + j0 + 16 * mt);
        #pragma unroll
        for (int r = 0; r < 4; ++r) {
            const int j = j0 + 16 * mt + r;
            u[mt][r] = exp2f((trans[j * N_ + START_] + em[r]) * LOG2E);
        }
    }
    epilogue();

    // ---- main chain: t = 1..511, emit = inputs[:,t,:], m = mask[:,t-1]
    floatx4 e0 = *(const floatx4*)(emitp + N_ + j0);
    floatx4 e1 = *(const floatx4*)(emitp + N_ + j0 + 16);
    float mA = (float)mask[bg * T_ + 0];

    for (int t = 1; t <= T_ - 1; ++t) {
        const int tn = (t < T_ - 1) ? t + 1 : t;     // prefetch next step
        floatx4 f0 = *(const floatx4*)(emitp + (size_t)tn * N_ + j0);
        floatx4 f1 = *(const floatx4*)(emitp + (size_t)tn * N_ + j0 + 16);
        const float mB = (float)mask[bg * T_ + (tn - 1)];

        short8 bfrag[8];   // B[k=32kt+8q+jj][n=b] from Vlds[b][k]
        #pragma unroll
        for (int kt = 0; kt < 8; ++kt)
            bfrag[kt] = *(const short8*)&Vlds[b * VPITCH + kt * 32 + q * 8];

        floatx4 acc0 = {0.f, 0.f, 0.f, 0.f};
        floatx4 acc1 = {0.f, 0.f, 0.f, 0.f};
        #pragma unroll
        for (int kt = 0; kt < 8; ++kt) {
            acc0 = __builtin_amdgcn_mfma_f32_16x16x32_bf16(afrag[0][kt], bfrag[kt], acc0, 0, 0, 0);
            acc1 = __builtin_amdgcn_mfma_f32_16x16x32_bf16(afrag[1][kt], bfrag[kt], acc1, 0, 0, 0);
        }

        const bool live = (mA != 0.f);
        #pragma unroll
        for (int r = 0; r < 4; ++r) {
            u[0][r] = live ? acc0[r] * exp2f(e0[r] * LOG2E) : colsum;
            u[1][r] = live ? acc1[r] * exp2f(e1[r] * LOG2E) : colsum;
        }
        epilogue();
        e0 = f0; e1 = f1; mA = mB;
    }

    // ---- final: denom = ln2 * (C + log2(sum_j V[j]*2^(trans2[STOP,j])))
    float fin = 0.f;
    #pragma unroll
    for (int mt = 0; mt < 2; ++mt) {
        floatx4 st = *(const floatx4*)(trans + STOP_ * N_ + j0 + 16 * mt);
        #pragma unroll
        for (int r = 0; r < 4; ++r)
            fin += u[mt][r] * exp2f(st[r] * LOG2E);
    }
    fin += __shfl_xor(fin, 16, 64);
    fin += __shfl_xor(fin, 32, 64);
    if (l < 16) sbuf[b * 8 + w] = fin;
    __syncthreads();
    if (tid < 16) {           // b == tid, C is this column's offset
        float tot = 0.f;
        #pragma unroll
        for (int ww = 0; ww < 8; ++ww) tot += sbuf[tid * 8 + ww];
        const float denom = (C + log2f(tot)) * LN2;
        atomicAdd(out, -denom);
    }
}

extern "C" void kernel_launch(void* const* d_in, const int* in_sizes, int n_in,
                              void* d_out, int out_size, void* d_ws, size_t ws_size,
                              hipStream_t stream) {
    const float* inputs = (const float*)d_in[0];
    const float* trans  = (const float*)d_in[1];
    const int*   tags   = (const int*)d_in[2];
    const int*   mask   = (const int*)d_in[3];
    float* out = (float*)d_out;
    hipMemsetAsync(out, 0, sizeof(float), stream);
    dim3 grid(NDB + B_);     // 16 denominator blocks + 256 numerator blocks
    dim3 block(512);
    crf_kernel<<<grid, block, 0, stream>>>(inputs, trans, tags, mask, out);
}

// Round 2
// 670.772 us; speedup vs baseline: 1.1117x; 1.1117x over previous
//
#include <hip/hip_runtime.h>
#include <hip/hip_bf16.h>
#include <stdint.h>

#define B_    256
#define T_    512
#define N_    256
#define START_ 254
#define STOP_  255
#define GCOLS 16
#define NDB   (B_ / GCOLS)   // 16 denominator blocks
#define LOG2E 1.4426950408889634f
#define LN2   0.6931471805599453f
#define VPITCH 264           // shorts per V row; 528 B => 2-way bank aliasing (free)

typedef __attribute__((ext_vector_type(8))) short short8;
typedef __attribute__((ext_vector_type(4))) short short4_t;
typedef __attribute__((ext_vector_type(4))) float floatx4;

__device__ __forceinline__ short f2bf(float f) {        // RNE (one-time E build)
    uint32_t u = __builtin_bit_cast(uint32_t, f);
    u = (u + 0x7FFFu + ((u >> 16) & 1u)) >> 16;
    return (short)(uint16_t)u;
}
__device__ __forceinline__ short f2bf_fast(float f) {   // round-half-up (per step)
    uint32_t u = __builtin_bit_cast(uint32_t, f);
    return (short)((u + 0x8000u) >> 16);
}

// lgkm-only barrier: LDS produced data is drained, but global (vmcnt) prefetch
// stays in flight across the barrier (unlike __syncthreads which drains vmcnt(0)).
__device__ __forceinline__ void lds_barrier() {
    asm volatile("s_waitcnt lgkmcnt(0)\n\ts_barrier" ::: "memory");
}

// Denominator block: 512 threads = 8 waves. Wave w owns rows [32w,32w+32).
// Lane l: q=l>>4, b=l&15 (batch column). E=exp(trans) bf16 lives in VGPRs as
// persistent MFMA A-fragments. V (16 cols x 256 states, bf16) double-buffered
// in LDS. Normalization deferred: full cross-wave epilogue every 4th step only
// (worst-case growth 2^16.2/step; 4 steps = 2^65 < f32 range).
__global__ __launch_bounds__(512, 2) void crf_kernel(
    const float* __restrict__ inputs, const float* __restrict__ trans,
    const int* __restrict__ tags, const int* __restrict__ mask,
    float* __restrict__ out)
{
    __shared__ __align__(16) short Vlds[2][GCOLS * VPITCH];
    __shared__ __align__(16) float mbuf[GCOLS * 8];
    __shared__ __align__(16) float sbuf[GCOLS * 8];
    __shared__ float nred[8];
    __shared__ int   nredi[8];

    if (blockIdx.x >= NDB) {
        // ---------------- numerator path: one batch per block ----------------
        const int bb = blockIdx.x - NDB;
        const int t  = threadIdx.x;            // 0..511
        const int tg = tags[bb * T_ + t];
        const float fm = (float)mask[bb * T_ + t];
        float part = 0.f;
        if (t >= 1)      part += trans[tg * N_ + tags[bb * T_ + t - 1]] * fm;
        if (t <= T_ - 2) part += inputs[((size_t)bb * T_ + t) * N_ + tg] * fm;
        int ms = mask[bb * T_ + t];
        #pragma unroll
        for (int off = 1; off < 64; off <<= 1) {
            part += __shfl_xor(part, off, 64);
            ms   += __shfl_xor(ms, off, 64);
        }
        if ((t & 63) == 0) { nred[t >> 6] = part; nredi[t >> 6] = ms; }
        __syncthreads();
        if (t == 0) {
            float tot = 0.f; int mtot = 0;
            for (int i = 0; i < 8; ++i) { tot += nred[i]; mtot += nredi[i]; }
            tot += trans[tags[bb * T_] * N_ + START_];
            const int last = mtot - 1;
            const int lt = tags[bb * T_ + last];
            tot += trans[STOP_ * N_ + lt]
                 + inputs[((size_t)bb * T_ + (T_ - 1)) * N_ + lt]
                   * (float)mask[bb * T_ + T_ - 1];
            atomicAdd(out, tot);
        }
        return;
    }

    // ---------------- denominator path ----------------
    const int tid = threadIdx.x;
    const int w = tid >> 6;          // wave 0..7
    const int l = tid & 63;
    const int q = l >> 4;            // quad 0..3
    const int b = l & 15;            // batch column
    const int bg = blockIdx.x * GCOLS + b;
    const int j0 = 32 * w + 4 * q;   // C/D row base (+16*mt)
    const int voff = b * VPITCH;

    // ---- persistent A-fragments: lane holds E[32w+16mt+b][32kt+8q+jj]
    short8 afrag[2][8];
    #pragma unroll
    for (int mt = 0; mt < 2; ++mt) {
        const int row = 32 * w + 16 * mt + b;
        #pragma unroll
        for (int kt = 0; kt < 8; ++kt) {
            const float* p = trans + row * N_ + kt * 32 + q * 8;
            floatx4 t0 = *(const floatx4*)p;
            floatx4 t1 = *(const floatx4*)(p + 4);
            short8 a;
            a[0] = f2bf(__builtin_amdgcn_exp2f(t0[0] * LOG2E));
            a[1] = f2bf(__builtin_amdgcn_exp2f(t0[1] * LOG2E));
            a[2] = f2bf(__builtin_amdgcn_exp2f(t0[2] * LOG2E));
            a[3] = f2bf(__builtin_amdgcn_exp2f(t0[3] * LOG2E));
            a[4] = f2bf(__builtin_amdgcn_exp2f(t1[0] * LOG2E));
            a[5] = f2bf(__builtin_amdgcn_exp2f(t1[1] * LOG2E));
            a[6] = f2bf(__builtin_amdgcn_exp2f(t1[2] * LOG2E));
            a[7] = f2bf(__builtin_amdgcn_exp2f(t1[3] * LOG2E));
            afrag[mt][kt] = a;
        }
    }

    const float* emitp = inputs + (size_t)bg * T_ * N_;
    const int*   maskp = mask + bg * T_;
    float C = 0.f;        // per-column log2-scale offset
    float colsum = 0.f;   // sum_i V[i,b] (only consumed when mask==0; mask is ones here)
    float u[2][4];
    int ph = 0;           // Vlds[ph] holds current alpha

    auto writeV = [&](int p) {
        short4_t v0, v1;
        #pragma unroll
        for (int r = 0; r < 4; ++r) { v0[r] = f2bf_fast(u[0][r]); v1[r] = f2bf_fast(u[1][r]); }
        *(short4_t*)&Vlds[p][voff + j0]      = v0;
        *(short4_t*)&Vlds[p][voff + j0 + 16] = v1;
    };

    auto full_epi = [&](int p) {   // normalize u by column max, track C, write V
        float mx = 0.f, sm = 0.f;  // u >= 0
        #pragma unroll
        for (int mt = 0; mt < 2; ++mt)
            #pragma unroll
            for (int r = 0; r < 4; ++r) { mx = fmaxf(mx, u[mt][r]); sm += u[mt][r]; }
        mx = fmaxf(mx, __shfl_xor(mx, 16, 64)); sm += __shfl_xor(sm, 16, 64);
        mx = fmaxf(mx, __shfl_xor(mx, 32, 64)); sm += __shfl_xor(sm, 32, 64);
        if (l < 16) { mbuf[b * 8 + w] = mx; sbuf[b * 8 + w] = sm; }
        lds_barrier();
        floatx4 m0 = *(const floatx4*)&mbuf[b * 8];
        floatx4 m1 = *(const floatx4*)&mbuf[b * 8 + 4];
        floatx4 s0 = *(const floatx4*)&sbuf[b * 8];
        floatx4 s1 = *(const floatx4*)&sbuf[b * 8 + 4];
        float cmax = fmaxf(fmaxf(fmaxf(m0[0], m0[1]), fmaxf(m0[2], m0[3])),
                           fmaxf(fmaxf(m1[0], m1[1]), fmaxf(m1[2], m1[3])));
        float csum = ((s0[0] + s0[1]) + (s0[2] + s0[3])) +
                     ((s1[0] + s1[1]) + (s1[2] + s1[3]));
        float rs = __builtin_amdgcn_rcpf(cmax);
        C -= __builtin_amdgcn_logf(rs);      // v_log_f32 = log2; exact bookkeeping of applied rs
        colsum = csum * rs;
        #pragma unroll
        for (int mt = 0; mt < 2; ++mt)
            #pragma unroll
            for (int r = 0; r < 4; ++r) u[mt][r] *= rs;
        writeV(p);
        lds_barrier();
    };

    // ---- init: alpha0 = exp(trans[:,START] + inputs[:,0,:])
    #pragma unroll
    for (int mt = 0; mt < 2; ++mt) {
        floatx4 em = *(const floatx4*)(emitp + j0 + 16 * mt);
        #pragma unroll
        for (int r = 0; r < 4; ++r) {
            const int j = j0 + 16 * mt + r;
            u[mt][r] = __builtin_amdgcn_exp2f((trans[j * N_ + START_] + em[r]) * LOG2E);
        }
    }
    full_epi(0);
    ph = 0;

    // ---- prefetch state: eA = emit(t), eB = emit(t+1); mA = mask[t-1], mB = mask[t]
    floatx4 eA0 = *(const floatx4*)(emitp + N_ + j0);
    floatx4 eA1 = *(const floatx4*)(emitp + N_ + j0 + 16);
    floatx4 eB0 = *(const floatx4*)(emitp + 2 * (size_t)N_ + j0);
    floatx4 eB1 = *(const floatx4*)(emitp + 2 * (size_t)N_ + j0 + 16);
    float mA = (float)maskp[0];
    float mB = (float)maskp[1];

    auto step = [&](int t, bool full) {
        const int tp = (t + 2 <= T_ - 1) ? t + 2 : T_ - 1;   // distance-2 prefetch
        floatx4 eC0 = *(const floatx4*)(emitp + (size_t)tp * N_ + j0);
        floatx4 eC1 = *(const floatx4*)(emitp + (size_t)tp * N_ + j0 + 16);
        const float mC = (float)maskp[tp - 1];

        const short* vb = &Vlds[ph][voff];
        short8 bfrag[8];
        #pragma unroll
        for (int kt = 0; kt < 8; ++kt)
            bfrag[kt] = *(const short8*)&vb[kt * 32 + q * 8];

        // overlap transcendental with LDS wait
        float xp0[4], xp1[4];
        #pragma unroll
        for (int r = 0; r < 4; ++r) {
            xp0[r] = __builtin_amdgcn_exp2f(eA0[r] * LOG2E);
            xp1[r] = __builtin_amdgcn_exp2f(eA1[r] * LOG2E);
        }

        floatx4 a0 = {0.f,0.f,0.f,0.f}, a1 = {0.f,0.f,0.f,0.f};
        floatx4 a2 = {0.f,0.f,0.f,0.f}, a3 = {0.f,0.f,0.f,0.f};
        #pragma unroll
        for (int kt = 0; kt < 4; ++kt) {   // two 4-deep half-chains per M-tile
            a0 = __builtin_amdgcn_mfma_f32_16x16x32_bf16(afrag[0][kt],     bfrag[kt],     a0, 0, 0, 0);
            a1 = __builtin_amdgcn_mfma_f32_16x16x32_bf16(afrag[0][kt + 4], bfrag[kt + 4], a1, 0, 0, 0);
            a2 = __builtin_amdgcn_mfma_f32_16x16x32_bf16(afrag[1][kt],     bfrag[kt],     a2, 0, 0, 0);
            a3 = __builtin_amdgcn_mfma_f32_16x16x32_bf16(afrag[1][kt + 4], bfrag[kt + 4], a3, 0, 0, 0);
        }

        const bool live = (mA != 0.f);
        #pragma unroll
        for (int r = 0; r < 4; ++r) {
            u[0][r] = live ? (a0[r] + a1[r]) * xp0[r] : colsum;
            u[1][r] = live ? (a2[r] + a3[r]) * xp1[r] : colsum;
        }
        if (full) {
            full_epi(ph ^ 1);
        } else {
            writeV(ph ^ 1);
            lds_barrier();
        }
        ph ^= 1;
        eA0 = eB0; eA1 = eB1; eB0 = eC0; eB1 = eC1;
        mA = mB; mB = mC;
    };

    // t = 1..511; full normalization every 4th step (overflow-safe: <=2^65)
    for (int g = 0; g < 127; ++g) {
        const int t = 4 * g + 1;
        step(t,     false);
        step(t + 1, false);
        step(t + 2, false);
        step(t + 3, true);
    }
    step(509, false);
    step(510, false);
    step(511, false);

    // ---- final: denom = ln2 * (C + log2(sum_j u[j]*2^(trans2[STOP,j])))
    float fin = 0.f;
    #pragma unroll
    for (int mt = 0; mt < 2; ++mt) {
        floatx4 st = *(const floatx4*)(trans + STOP_ * N_ + j0 + 16 * mt);
        #pragma unroll
        for (int r = 0; r < 4; ++r)
            fin += u[mt][r] * __builtin_amdgcn_exp2f(st[r] * LOG2E);
    }
    fin += __shfl_xor(fin, 16, 64);
    fin += __shfl_xor(fin, 32, 64);
    if (l < 16) sbuf[b * 8 + w] = fin;
    __syncthreads();
    if (tid < 16) {           // b == tid
        float tot = 0.f;
        #pragma unroll
        for (int ww = 0; ww < 8; ++ww) tot += sbuf[tid * 8 + ww];
        const float denom = (C + __builtin_amdgcn_logf(tot)) * LN2;
        atomicAdd(out, -denom);
    }
}

extern "C" void kernel_launch(void* const* d_in, const int* in_sizes, int n_in,
                              void* d_out, int out_size, void* d_ws, size_t ws_size,
                              hipStream_t stream) {
    const float* inputs = (const float*)d_in[0];
    const float* trans  = (const float*)d_in[1];
    const int*   tags   = (const int*)d_in[2];
    const int*   mask   = (const int*)d_in[3];
    float* out = (float*)d_out;
    hipMemsetAsync(out, 0, sizeof(float), stream);
    dim3 grid(NDB + B_);     // 16 denominator blocks + 256 numerator blocks
    dim3 block(512);
    crf_kernel<<<grid, block, 0, stream>>>(inputs, trans, tags, mask, out);
}